// Round 3
// baseline (977.336 us; speedup 1.0000x reference)
//
#include <hip/hip_runtime.h>

// Mamba selective scan, fp32. u,delta,z:(4,2048,2048) A:(2048,16)
// B,C:(4,16,2048) D:(2048,). Output y:(4,2048,2048).
// 3-pass chunked scan (chunk op = (S=sum dt, q=local scan)); 64 chunks of 32 t.
// R6: DRAM page density. R5's stage insts touched 8 rows x 128B at 8KB
// stride -> ~128B per HBM page activation -> ~2-2.5 TB/s cap on every pass.
// Now: thread = one 32-t chunk (= one 128B line per stream); block = 32 ch
// x 8 consecutive chunks (256-t window). A wave's 8-load group covers
// 8 rows x 1KB CONTIGUOUS. u/delta/z/out skip LDS entirely (per-thread
// contiguous f4 runs); only B/C staged in LDS, conflict-free both sides
// (stage: f4-along-n at t*20, slot (5t+m)&7 bijective; compute: 8-addr
// broadcast = minimum passes). ws re-keyed [n][tau][g][ch][seg] so state
// I/O is dense 256B/wave-inst. pass2: f4 loads + 1-window register
// prefetch (breaks the may-alias serial-latency chain).

#define BATCHSZ 4
#define DIN 2048
#define NSTATE 16
#define SEQ 2048
#define NCH (BATCHSZ * DIN)     // 8192 channels
#define CHG 32                  // channels per block
#define SEGS 8                  // chunks (threads) per channel per block
#define SLEN 32                 // chunk length (= 128 B per stream)
#define WIN 256                 // t-window per block = SEGS*SLEN
#define NWIN 8                  // SEQ/WIN
#define NCP 64                  // total chunks per channel = NWIN*SEGS
#define NG2 256                 // NCH/CHG channel groups
#define L2E 1.44269504f

// ws float-index strides (layout [n][tau][g][ch][seg]):
//   n: 524288 (=NWIN*NG2*CHG*SEGS), tau: 65536, g: 256, ch: 8, seg: 1
//   wsS at float offset 8388608 (=NSTATE*524288), same [tau][g][ch][seg].
#define WSQ_N 524288
#define WSQ_T 65536
#define WSS_OFF 8388608

__device__ __forceinline__ float softplus_f(float v) {
    float e = __builtin_amdgcn_exp2f(v * L2E);
    return 0.69314718f * __builtin_amdgcn_logf(1.0f + e);
}

__device__ __forceinline__ float silu_f(float v) {
    float s = __builtin_amdgcn_rcpf(1.0f + __builtin_amdgcn_exp2f(-v * L2E));
    return v * s;
}

__device__ __forceinline__ float comp4(const float4& f, int k) {
    return k == 0 ? f.x : k == 1 ? f.y : k == 2 ? f.z : f.w;
}

__device__ __forceinline__ void set4(float4& f, int k, float v) {
    if (k == 0) f.x = v; else if (k == 1) f.y = v; else if (k == 2) f.z = v; else f.w = v;
}

// Pass 1: thread = (channel, 32-t chunk); block = 32 ch x 8 chunks (256-t
// window). Local scan from zero -> (q[16], S) per chunk.
__global__ __launch_bounds__(256, 3) void k_pass1(
        const float* __restrict__ u, const float* __restrict__ delta,
        const float* __restrict__ A, const float* __restrict__ Bm,
        float* __restrict__ ws) {
    __shared__ float Bc[WIN * 20];         // [t_local][16 n + 4 pad]

    int tid = threadIdx.x;
    int g = blockIdx.x & (NG2 - 1);
    int tau = blockIdx.x >> 8;             // wave-uniform
    int ch = tid >> 3, seg = tid & 7;
    int bd = g * CHG + ch;
    int d = bd & (DIN - 1);
    int b = bd >> 11;                      // block-uniform (32 | 2048)

    // Per-thread slice: one 128B line per stream; wave footprint = 8 rows x 1KB.
    const float* up = u + (size_t)bd * SEQ + tau * WIN + seg * SLEN;
    const float* dp = delta + (size_t)bd * SEQ + tau * WIN + seg * SLEN;
    float4 uv[8], dv[8];
    #pragma unroll
    for (int j = 0; j < 8; ++j) { uv[j] = ((const float4*)up)[j]; dv[j] = ((const float4*)dp)[j]; }

    // Stage B window transposed to [t][n]. Loads: 4 x b32, dense 256B/inst.
    // LDS writes: f4 at Bc[t*20 + m*4], slot (5t+m)&7 bijective -> conflict-free.
    const float* Bg = Bm + (size_t)b * NSTATE * SEQ + tau * WIN;
    #pragma unroll
    for (int m = 0; m < 4; ++m) {
        float4 v;
        v.x = Bg[(size_t)(m * 4 + 0) * SEQ + tid];
        v.y = Bg[(size_t)(m * 4 + 1) * SEQ + tid];
        v.z = Bg[(size_t)(m * 4 + 2) * SEQ + tid];
        v.w = Bg[(size_t)(m * 4 + 3) * SEQ + tid];
        *(float4*)(&Bc[tid * 20 + m * 4]) = v;
    }

    float A2[NSTATE];
    const float* Ar = A + (size_t)d * NSTATE;
    #pragma unroll
    for (int n = 0; n < NSTATE; ++n) A2[n] = Ar[n] * L2E;

    __syncthreads();

    float x[NSTATE];
    #pragma unroll
    for (int n = 0; n < NSTATE; ++n) x[n] = 0.0f;
    float S = 0.0f;

    #pragma unroll
    for (int j = 0; j < 8; ++j) {
        #pragma unroll
        for (int k = 0; k < 4; ++k) {
            float dt = softplus_f(comp4(dv[j], k));
            S += dt;
            float du = dt * comp4(uv[j], k);
            int tl = seg * SLEN + j * 4 + k;
            const float4* Br = (const float4*)(&Bc[tl * 20]);
            float bb[NSTATE];
            *(float4*)&bb[0] = Br[0]; *(float4*)&bb[4] = Br[1];
            *(float4*)&bb[8] = Br[2]; *(float4*)&bb[12] = Br[3];
            #pragma unroll
            for (int n = 0; n < NSTATE; ++n) {
                float dA = __builtin_amdgcn_exp2f(A2[n] * dt);
                x[n] = x[n] * dA + du * bb[n];
            }
        }
    }

    // Dense state write: per inst, (ch,seg) lanes cover 256B contiguous.
    size_t qb = (size_t)tau * WSQ_T + (size_t)g * 256 + ch * 8 + seg;
    #pragma unroll
    for (int n = 0; n < NSTATE; ++n) ws[(size_t)n * WSQ_N + qb] = x[n];
    ws[WSS_OFF + qb] = S;
}

// Pass 2: combine 64 chunk operators per (n, bd); f4-granular with one-window
// register prefetch. In-place overwrite q -> chunk-initial prefix.
__global__ __launch_bounds__(256) void k_pass2(
        const float* __restrict__ A, float* __restrict__ ws) {
    int idx = blockIdx.x * 256 + threadIdx.x;   // 0 .. 16*8192-1
    int n = idx >> 13;
    int bd = idx & (NCH - 1);
    int g = bd >> 5, ch = bd & 31;
    int d = bd & (DIN - 1);

    float A2 = A[(size_t)d * NSTATE + n] * L2E;

    size_t qb = (size_t)n * WSQ_N + (size_t)g * 256 + ch * 8;   // seg=0
    size_t sb = WSS_OFF + (size_t)g * 256 + ch * 8;

    float x = 0.0f;
    float4 Sa = *(const float4*)(ws + sb);
    float4 Sb = *(const float4*)(ws + sb + 4);
    float4 qa = *(const float4*)(ws + qb);
    float4 q2 = *(const float4*)(ws + qb + 4);

    #pragma unroll
    for (int tau = 0; tau < NWIN; ++tau) {
        float4 nSa, nSb, nqa, nq2;
        if (tau + 1 < NWIN) {               // prefetch next window first
            nSa = *(const float4*)(ws + sb + (size_t)(tau + 1) * WSQ_T);
            nSb = *(const float4*)(ws + sb + (size_t)(tau + 1) * WSQ_T + 4);
            nqa = *(const float4*)(ws + qb + (size_t)(tau + 1) * WSQ_T);
            nq2 = *(const float4*)(ws + qb + (size_t)(tau + 1) * WSQ_T + 4);
        }
        float Sv[8], qv[8], xs[8];
        *(float4*)&Sv[0] = Sa; *(float4*)&Sv[4] = Sb;
        *(float4*)&qv[0] = qa; *(float4*)&qv[4] = q2;
        #pragma unroll
        for (int s = 0; s < 8; ++s) {
            xs[s] = x;
            x = x * __builtin_amdgcn_exp2f(A2 * Sv[s]) + qv[s];
        }
        *(float4*)(ws + qb + (size_t)tau * WSQ_T) = *(float4*)&xs[0];
        *(float4*)(ws + qb + (size_t)tau * WSQ_T + 4) = *(float4*)&xs[4];
        Sa = nSa; Sb = nSb; qa = nqa; q2 = nq2;
    }
}

// Pass 3: rescan each chunk from its initial state; emit gated y.
__global__ __launch_bounds__(256, 3) void k_pass3(
        const float* __restrict__ u, const float* __restrict__ delta,
        const float* __restrict__ A, const float* __restrict__ Bm,
        const float* __restrict__ Cm, const float* __restrict__ Dv,
        const float* __restrict__ z, const float* __restrict__ ws,
        float* __restrict__ out) {
    __shared__ float Bc[WIN * 20];
    __shared__ float Cc[WIN * 20];

    int tid = threadIdx.x;
    int g = blockIdx.x & (NG2 - 1);
    int tau = blockIdx.x >> 8;
    int ch = tid >> 3, seg = tid & 7;
    int bd = g * CHG + ch;
    int d = bd & (DIN - 1);
    int b = bd >> 11;

    // Chunk-initial state (dense 256B/wave-inst reads; pass2-warm in L2/L3).
    size_t qb = (size_t)tau * WSQ_T + (size_t)g * 256 + ch * 8 + seg;
    float x[NSTATE];
    #pragma unroll
    for (int n = 0; n < NSTATE; ++n) x[n] = ws[(size_t)n * WSQ_N + qb];

    const float* up = u + (size_t)bd * SEQ + tau * WIN + seg * SLEN;
    const float* dp = delta + (size_t)bd * SEQ + tau * WIN + seg * SLEN;
    float4 uv[8], dv[8];
    #pragma unroll
    for (int j = 0; j < 8; ++j) { uv[j] = ((const float4*)up)[j]; dv[j] = ((const float4*)dp)[j]; }

    const float* Bg = Bm + (size_t)b * NSTATE * SEQ + tau * WIN;
    const float* Cg = Cm + (size_t)b * NSTATE * SEQ + tau * WIN;
    #pragma unroll
    for (int m = 0; m < 4; ++m) {
        float4 v, w;
        v.x = Bg[(size_t)(m * 4 + 0) * SEQ + tid];
        v.y = Bg[(size_t)(m * 4 + 1) * SEQ + tid];
        v.z = Bg[(size_t)(m * 4 + 2) * SEQ + tid];
        v.w = Bg[(size_t)(m * 4 + 3) * SEQ + tid];
        w.x = Cg[(size_t)(m * 4 + 0) * SEQ + tid];
        w.y = Cg[(size_t)(m * 4 + 1) * SEQ + tid];
        w.z = Cg[(size_t)(m * 4 + 2) * SEQ + tid];
        w.w = Cg[(size_t)(m * 4 + 3) * SEQ + tid];
        *(float4*)(&Bc[tid * 20 + m * 4]) = v;
        *(float4*)(&Cc[tid * 20 + m * 4]) = w;
    }

    float A2[NSTATE];
    const float* Ar = A + (size_t)d * NSTATE;
    #pragma unroll
    for (int n = 0; n < NSTATE; ++n) A2[n] = Ar[n] * L2E;
    float Dd = Dv[d];

    __syncthreads();

    #pragma unroll
    for (int j = 0; j < 8; ++j) {
        #pragma unroll
        for (int k = 0; k < 4; ++k) {
            float uvk = comp4(uv[j], k);
            float dt = softplus_f(comp4(dv[j], k));
            float du = dt * uvk;
            int tl = seg * SLEN + j * 4 + k;
            const float4* Br = (const float4*)(&Bc[tl * 20]);
            const float4* Cr = (const float4*)(&Cc[tl * 20]);
            float bb[NSTATE], cc[NSTATE];
            *(float4*)&bb[0] = Br[0]; *(float4*)&bb[4] = Br[1];
            *(float4*)&bb[8] = Br[2]; *(float4*)&bb[12] = Br[3];
            *(float4*)&cc[0] = Cr[0]; *(float4*)&cc[4] = Cr[1];
            *(float4*)&cc[8] = Cr[2]; *(float4*)&cc[12] = Cr[3];
            float acc = 0.0f;
            #pragma unroll
            for (int n = 0; n < NSTATE; ++n) {
                float dA = __builtin_amdgcn_exp2f(A2[n] * dt);
                x[n] = x[n] * dA + du * bb[n];
                acc += x[n] * cc[n];
            }
            set4(uv[j], k, acc + Dd * uvk);    // y overwrites u in regs
        }
    }

    const float* zp = z + (size_t)bd * SEQ + tau * WIN + seg * SLEN;
    float* op = out + (size_t)bd * SEQ + tau * WIN + seg * SLEN;
    float4 zv[8];
    #pragma unroll
    for (int j = 0; j < 8; ++j) zv[j] = ((const float4*)zp)[j];
    #pragma unroll
    for (int j = 0; j < 8; ++j) {
        float4 oo;
        #pragma unroll
        for (int k = 0; k < 4; ++k)
            set4(oo, k, comp4(uv[j], k) * silu_f(comp4(zv[j], k)));
        ((float4*)op)[j] = oo;
    }
}

// Fallback if ws is too small: one thread per (b,d), full sequential scan.
__global__ __launch_bounds__(256) void k_simple(
        const float* __restrict__ u, const float* __restrict__ delta,
        const float* __restrict__ A, const float* __restrict__ Bm,
        const float* __restrict__ Cm, const float* __restrict__ Dv,
        const float* __restrict__ z, float* __restrict__ out) {
    int bd = blockIdx.x * 256 + threadIdx.x;
    int b  = bd >> 11;
    int d  = bd & (DIN - 1);

    float A2[NSTATE];
    const float* Ar = A + d * NSTATE;
    #pragma unroll
    for (int n = 0; n < NSTATE; ++n) A2[n] = Ar[n] * L2E;
    float x[NSTATE];
    #pragma unroll
    for (int n = 0; n < NSTATE; ++n) x[n] = 0.0f;

    float Dd = Dv[d];
    size_t base = (size_t)bd * SEQ;
    const float4* u4 = (const float4*)(u + base);
    const float4* d4 = (const float4*)(delta + base);
    const float4* z4 = (const float4*)(z + base);
    float4* o4 = (float4*)(out + base);
    const float* Bp = Bm + (size_t)b * NSTATE * SEQ;
    const float* Cp = Cm + (size_t)b * NSTATE * SEQ;

    for (int t4 = 0; t4 < SEQ / 4; ++t4) {
        float4 uu = u4[t4];
        float4 dd = d4[t4];
        float4 zz = z4[t4];
        float4 yy;
        #pragma unroll
        for (int k = 0; k < 4; ++k) {
            float uvk = comp4(uu, k);
            float dt = softplus_f(comp4(dd, k));
            float du = dt * uvk;
            int t = t4 * 4 + k;
            float acc = 0.0f;
            #pragma unroll
            for (int n = 0; n < NSTATE; ++n) {
                float dA = __builtin_amdgcn_exp2f(A2[n] * dt);
                x[n] = x[n] * dA + du * Bp[n * SEQ + t];
                acc += x[n] * Cp[n * SEQ + t];
            }
            float y = acc + Dd * uvk;
            y = y * silu_f(comp4(zz, k));
            set4(yy, k, y);
        }
        o4[t4] = yy;
    }
}

extern "C" void kernel_launch(void* const* d_in, const int* in_sizes, int n_in,
                              void* d_out, int out_size, void* d_ws, size_t ws_size,
                              hipStream_t stream) {
    const float* u     = (const float*)d_in[0];
    const float* delta = (const float*)d_in[1];
    const float* A     = (const float*)d_in[2];
    const float* Bm    = (const float*)d_in[3];
    const float* Cm    = (const float*)d_in[4];
    const float* Dv    = (const float*)d_in[5];
    const float* z     = (const float*)d_in[6];
    float* out = (float*)d_out;
    float* ws = (float*)d_ws;

    size_t need = (size_t)(NSTATE + 1) * NCP * NCH * sizeof(float);   // 35.65 MB
    if (ws_size >= need) {
        k_pass1<<<NWIN * NG2, 256, 0, stream>>>(u, delta, A, Bm, ws);
        k_pass2<<<(NSTATE * NCH) / 256, 256, 0, stream>>>(A, ws);
        k_pass3<<<NWIN * NG2, 256, 0, stream>>>(u, delta, A, Bm, Cm, Dv, z, ws, out);
    } else {
        k_simple<<<NCH / 256, 256, 0, stream>>>(u, delta, A, Bm, Cm, Dv, z, out);
    }
}

// Round 4
// 369.126 us; speedup vs baseline: 2.6477x; 2.6477x over previous
//
#include <hip/hip_runtime.h>

// Mamba selective scan, fp32. u,delta,z:(4,2048,2048) A:(2048,16)
// B,C:(4,16,2048) D:(2048,). Output y:(4,2048,2048).
// 3-pass chunked scan (chunk op = (S=sum dt, q=local scan)).
// R8: R5 structure (thread=channel, LDS transpose, proven 378us) with the
// overlap fixed. R5 was stuck at 2.5 TB/s because barriers locked all 8
// waves of a block into stage|compute|drain phase alignment with only
// 2 blocks/CU (77KB LDS). Changes:
//  - 16-t subtiles: stream LDS 2x36KB -> 2x20KB, total 45KB -> 3 blocks/CU.
//    Both 64B halves of each 128B line are touched by the SAME block ~1us
//    apart (L2-resident), so no refetch; TA sector count unchanged.
//  - Wave-private staging: wave w stages exactly rows [64w,64w+64) that its
//    own threads consume. Intra-wave lockstep => no barrier needed in the
//    t-loop (single __syncthreads for shared B/C). Waves free-run and
//    stagger -> memory issue decorrelated across 12 waves/CU.
//  - pass2: split restrict wsq/wsS pointers + batch-4 loads (kills the
//    may-alias serial latency chain).
//  - rule #20 hygiene: no register array is indexed by a big-loop var.
// (R6/R7 thread-owns-chunk branch abandoned: unrolled-array spill caused
// 1.3GB scratch traffic, and its stream I/O is inherently 64-lines/inst.)

#define BATCHSZ 4
#define DIN 2048
#define NSTATE 16
#define SEQ 2048
#define NCH (BATCHSZ * DIN)     // 8192 channels
#define NGRP (NCH / 256)        // 32 channel-groups of 256
#define SUB 16                  // t per subtile stage
#define ST 20                   // LDS row stride (floats), 16B-aligned
#define L2E 1.44269504f

__device__ __forceinline__ float softplus_f(float v) {
    float e = __builtin_amdgcn_exp2f(v * L2E);
    return 0.69314718f * __builtin_amdgcn_logf(1.0f + e);
}

__device__ __forceinline__ float silu_f(float v) {
    float s = __builtin_amdgcn_rcpf(1.0f + __builtin_amdgcn_exp2f(-v * L2E));
    return v * s;
}

__device__ __forceinline__ float comp4(const float4& f, int k) {
    return k == 0 ? f.x : k == 1 ? f.y : k == 2 ? f.z : f.w;
}

__device__ __forceinline__ void set4(float4& f, int k, float v) {
    if (k == 0) f.x = v; else if (k == 1) f.y = v; else if (k == 2) f.z = v; else f.w = v;
}

// ws layout (R5's, SoA, coalesced):
//   wsq[(n*NC + c)*NCH + bd]   n in [0,16)
//   wsS[c*NCH + bd]            (separate pointer)

// Pass 1: per (256-channel group, chunk) local scan from zero -> (q[16], S).
template<int NC>
__global__ __launch_bounds__(256, 3) void k_pass1(
        const float* __restrict__ u, const float* __restrict__ delta,
        const float* __restrict__ A, const float* __restrict__ Bm,
        float* __restrict__ wsq, float* __restrict__ wsS) {
    constexpr int LC = SEQ / NC;
    constexpr int NSUB = LC / SUB;
    __shared__ float Ub[256 * ST];
    __shared__ float Db[256 * ST];
    __shared__ float Bc[LC * 20];          // [t][16 n + 4 pad]

    int tid = threadIdx.x;
    int w6 = tid & ~63;                    // wave row base
    int l = tid & 63;
    int g = blockIdx.x & (NGRP - 1);
    int c = blockIdx.x >> 5;               // wave-uniform
    int chBase = g << 8;
    int b = chBase >> 11;
    int bd = chBase + tid;
    int d = bd & (DIN - 1);

    const float* ug = u + (size_t)chBase * SEQ + (size_t)c * LC;
    const float* dg = delta + (size_t)chBase * SEQ + (size_t)c * LC;
    const float* Bg = Bm + (size_t)b * NSTATE * SEQ + (size_t)c * LC;

    // Stage whole-chunk B transposed to [t][n] (lanes along t: dense).
    #pragma unroll
    for (int i = 0; i < LC * NSTATE / 256; ++i) {
        int e = i * 256 + tid;
        int n = e / LC;
        int t = e - n * LC;
        Bc[t * 20 + n] = Bg[(size_t)n * SEQ + t];
    }

    float A2[NSTATE];
    {
        const float* Ar = A + (size_t)d * NSTATE;
        #pragma unroll
        for (int n = 0; n < NSTATE; ++n) A2[n] = Ar[n] * L2E;
    }
    float x[NSTATE];
    #pragma unroll
    for (int n = 0; n < NSTATE; ++n) x[n] = 0.0f;
    float S = 0.0f;

    __syncthreads();                       // Bc ready; only barrier in kernel

    for (int st = 0; st < NSUB; ++st) {
        int tb = st * SUB;
        // Wave-private stage: 16 rows x 64B per inst, rows w6..w6+63.
        #pragma unroll
        for (int it = 0; it < 4; ++it) {
            int r = w6 + it * 16 + (l >> 2);
            int cq = (l & 3) << 2;
            *(float4*)(&Ub[r * ST + cq]) = *(const float4*)(ug + (size_t)r * SEQ + tb + cq);
            *(float4*)(&Db[r * ST + cq]) = *(const float4*)(dg + (size_t)r * SEQ + tb + cq);
        }
        // Intra-wave lockstep: own wave's ds_writes ordered before ds_reads.
        #pragma unroll
        for (int t4 = 0; t4 < SUB / 4; ++t4) {
            float4 u4 = *(const float4*)(&Ub[tid * ST + t4 * 4]);
            float4 d4 = *(const float4*)(&Db[tid * ST + t4 * 4]);
            #pragma unroll
            for (int k = 0; k < 4; ++k) {
                float dt = softplus_f(comp4(d4, k));
                S += dt;
                float du = dt * comp4(u4, k);
                int t = tb + t4 * 4 + k;
                const float4* Br = (const float4*)(&Bc[t * 20]);
                float bb[NSTATE];
                *(float4*)&bb[0] = Br[0]; *(float4*)&bb[4] = Br[1];
                *(float4*)&bb[8] = Br[2]; *(float4*)&bb[12] = Br[3];
                #pragma unroll
                for (int n = 0; n < NSTATE; ++n) {
                    float dA = __builtin_amdgcn_exp2f(A2[n] * dt);
                    x[n] = x[n] * dA + du * bb[n];
                }
            }
        }
    }

    #pragma unroll
    for (int n = 0; n < NSTATE; ++n) wsq[((size_t)n * NC + c) * NCH + bd] = x[n];
    wsS[(size_t)c * NCH + bd] = S;
}

// Pass 2: combine chunk operators, parallel over (n, bd); batch-4 loads,
// split restrict pointers so loads hoist past the in-place stores.
template<int NC>
__global__ __launch_bounds__(256) void k_pass2(
        const float* __restrict__ A, float* __restrict__ wsq,
        float* __restrict__ wsS) {
    int idx = blockIdx.x * 256 + threadIdx.x;   // 0 .. 16*8192-1
    int n = idx >> 13;
    int bd = idx & (NCH - 1);
    int d = bd & (DIN - 1);

    float A2 = A[(size_t)d * NSTATE + n] * L2E;
    float x = 0.0f;
    float* qbase = wsq + (size_t)n * NC * NCH + bd;

    for (int c0 = 0; c0 < NC; c0 += 4) {
        float S0 = wsS[(size_t)(c0 + 0) * NCH + bd];
        float S1 = wsS[(size_t)(c0 + 1) * NCH + bd];
        float S2 = wsS[(size_t)(c0 + 2) * NCH + bd];
        float S3 = wsS[(size_t)(c0 + 3) * NCH + bd];
        float* p0 = qbase + (size_t)(c0 + 0) * NCH;
        float* p1 = qbase + (size_t)(c0 + 1) * NCH;
        float* p2 = qbase + (size_t)(c0 + 2) * NCH;
        float* p3 = qbase + (size_t)(c0 + 3) * NCH;
        float q0 = *p0, q1 = *p1, q2 = *p2, q3 = *p3;
        float t0 = x; x = x * __builtin_amdgcn_exp2f(A2 * S0) + q0;
        float t1 = x; x = x * __builtin_amdgcn_exp2f(A2 * S1) + q1;
        float t2 = x; x = x * __builtin_amdgcn_exp2f(A2 * S2) + q2;
        float t3 = x; x = x * __builtin_amdgcn_exp2f(A2 * S3) + q3;
        *p0 = t0; *p1 = t1; *p2 = t2; *p3 = t3;   // chunk-initial prefixes
    }
}

// Pass 3: rescan from chunk-initial state; emit gated y. y transposes back
// through Ub (thread overwrites the exact b128 it consumed); z is read into
// registers during the wave-private stage (no transpose needed).
template<int NC>
__global__ __launch_bounds__(256, 3) void k_pass3(
        const float* __restrict__ u, const float* __restrict__ delta,
        const float* __restrict__ A, const float* __restrict__ Bm,
        const float* __restrict__ Cm, const float* __restrict__ Dv,
        const float* __restrict__ z, const float* __restrict__ wsq,
        float* __restrict__ out) {
    constexpr int LC = SEQ / NC;
    constexpr int NSUB = LC / SUB;
    __shared__ float Ub[256 * ST];          // u in compute, y for drain
    __shared__ float Db[256 * ST];
    __shared__ float Bc[LC * 20];
    __shared__ float Cc[LC * 20];

    int tid = threadIdx.x;
    int w6 = tid & ~63;
    int l = tid & 63;
    int g = blockIdx.x & (NGRP - 1);
    int c = blockIdx.x >> 5;
    int chBase = g << 8;
    int b = chBase >> 11;
    int bd = chBase + tid;
    int d = bd & (DIN - 1);

    const float* ug = u + (size_t)chBase * SEQ + (size_t)c * LC;
    const float* dg = delta + (size_t)chBase * SEQ + (size_t)c * LC;
    const float* zg = z + (size_t)chBase * SEQ + (size_t)c * LC;
    float* og = out + (size_t)chBase * SEQ + (size_t)c * LC;
    const float* Bg = Bm + (size_t)b * NSTATE * SEQ + (size_t)c * LC;
    const float* Cg = Cm + (size_t)b * NSTATE * SEQ + (size_t)c * LC;

    #pragma unroll
    for (int i = 0; i < LC * NSTATE / 256; ++i) {
        int e = i * 256 + tid;
        int n = e / LC;
        int t = e - n * LC;
        Bc[t * 20 + n] = Bg[(size_t)n * SEQ + t];
        Cc[t * 20 + n] = Cg[(size_t)n * SEQ + t];
    }

    float A2[NSTATE];
    {
        const float* Ar = A + (size_t)d * NSTATE;
        #pragma unroll
        for (int n = 0; n < NSTATE; ++n) A2[n] = Ar[n] * L2E;
    }
    float x[NSTATE];
    #pragma unroll
    for (int n = 0; n < NSTATE; ++n)
        x[n] = wsq[((size_t)n * NC + c) * NCH + bd];
    float Dd = Dv[d];

    __syncthreads();                       // Bc/Cc ready; only barrier

    for (int st = 0; st < NSUB; ++st) {
        int tb = st * SUB;
        float4 zr[4];
        #pragma unroll
        for (int it = 0; it < 4; ++it) {
            int r = w6 + it * 16 + (l >> 2);
            int cq = (l & 3) << 2;
            *(float4*)(&Ub[r * ST + cq]) = *(const float4*)(ug + (size_t)r * SEQ + tb + cq);
            *(float4*)(&Db[r * ST + cq]) = *(const float4*)(dg + (size_t)r * SEQ + tb + cq);
            zr[it] = *(const float4*)(zg + (size_t)r * SEQ + tb + cq);
        }
        #pragma unroll
        for (int t4 = 0; t4 < SUB / 4; ++t4) {
            float4 u4 = *(const float4*)(&Ub[tid * ST + t4 * 4]);
            float4 d4 = *(const float4*)(&Db[tid * ST + t4 * 4]);
            float4 y4;
            #pragma unroll
            for (int k = 0; k < 4; ++k) {
                float uv = comp4(u4, k);
                float dt = softplus_f(comp4(d4, k));
                float du = dt * uv;
                int t = tb + t4 * 4 + k;
                const float4* Br = (const float4*)(&Bc[t * 20]);
                const float4* Cr = (const float4*)(&Cc[t * 20]);
                float bb[NSTATE], cc[NSTATE];
                *(float4*)&bb[0] = Br[0]; *(float4*)&bb[4] = Br[1];
                *(float4*)&bb[8] = Br[2]; *(float4*)&bb[12] = Br[3];
                *(float4*)&cc[0] = Cr[0]; *(float4*)&cc[4] = Cr[1];
                *(float4*)&cc[8] = Cr[2]; *(float4*)&cc[12] = Cr[3];
                float acc = 0.0f;
                #pragma unroll
                for (int n = 0; n < NSTATE; ++n) {
                    float dA = __builtin_amdgcn_exp2f(A2[n] * dt);
                    x[n] = x[n] * dA + du * bb[n];
                    acc += x[n] * cc[n];
                }
                set4(y4, k, acc + Dd * uv);
            }
            // overwrite the exact u-b128 this thread just consumed
            *(float4*)(&Ub[tid * ST + t4 * 4]) = y4;
        }
        // Drain (same wave wrote these rows; lockstep => ordered).
        #pragma unroll
        for (int it = 0; it < 4; ++it) {
            int r = w6 + it * 16 + (l >> 2);
            int cq = (l & 3) << 2;
            float4 y4 = *(const float4*)(&Ub[r * ST + cq]);
            float4 oo;
            #pragma unroll
            for (int k = 0; k < 4; ++k)
                set4(oo, k, comp4(y4, k) * silu_f(comp4(zr[it], k)));
            *(float4*)(og + (size_t)r * SEQ + tb + cq) = oo;
        }
    }
}

// Fallback if ws is too small: one thread per (b,d), full sequential scan.
__global__ __launch_bounds__(256) void k_simple(
        const float* __restrict__ u, const float* __restrict__ delta,
        const float* __restrict__ A, const float* __restrict__ Bm,
        const float* __restrict__ Cm, const float* __restrict__ Dv,
        const float* __restrict__ z, float* __restrict__ out) {
    int bd = blockIdx.x * 256 + threadIdx.x;
    int b  = bd >> 11;
    int d  = bd & (DIN - 1);

    float A2[NSTATE];
    const float* Ar = A + d * NSTATE;
    #pragma unroll
    for (int n = 0; n < NSTATE; ++n) A2[n] = Ar[n] * L2E;
    float x[NSTATE];
    #pragma unroll
    for (int n = 0; n < NSTATE; ++n) x[n] = 0.0f;

    float Dd = Dv[d];
    size_t base = (size_t)bd * SEQ;
    const float4* u4 = (const float4*)(u + base);
    const float4* d4 = (const float4*)(delta + base);
    const float4* z4 = (const float4*)(z + base);
    float4* o4 = (float4*)(out + base);
    const float* Bp = Bm + (size_t)b * NSTATE * SEQ;
    const float* Cp = Cm + (size_t)b * NSTATE * SEQ;

    for (int t4 = 0; t4 < SEQ / 4; ++t4) {
        float4 uu = u4[t4];
        float4 dd = d4[t4];
        float4 zz = z4[t4];
        float4 yy;
        #pragma unroll
        for (int k = 0; k < 4; ++k) {
            float uvk = comp4(uu, k);
            float dt = softplus_f(comp4(dd, k));
            float du = dt * uvk;
            int t = t4 * 4 + k;
            float acc = 0.0f;
            #pragma unroll
            for (int n = 0; n < NSTATE; ++n) {
                float dA = __builtin_amdgcn_exp2f(A2[n] * dt);
                x[n] = x[n] * dA + du * Bp[n * SEQ + t];
                acc += x[n] * Cp[n * SEQ + t];
            }
            float y = acc + Dd * uvk;
            y = y * silu_f(comp4(zz, k));
            set4(yy, k, y);
        }
        o4[t4] = yy;
    }
}

template<int NC>
static void launch_chunked(const float* u, const float* delta, const float* A,
                           const float* Bm, const float* Cm, const float* Dv,
                           const float* z, float* ws, float* out, hipStream_t stream) {
    float* wsq = ws;
    float* wsS = ws + (size_t)NSTATE * NC * NCH;
    k_pass1<NC><<<NGRP * NC, 256, 0, stream>>>(u, delta, A, Bm, wsq, wsS);
    k_pass2<NC><<<(NSTATE * NCH) / 256, 256, 0, stream>>>(A, wsq, wsS);
    k_pass3<NC><<<NGRP * NC, 256, 0, stream>>>(u, delta, A, Bm, Cm, Dv, z, wsq, out);
}

extern "C" void kernel_launch(void* const* d_in, const int* in_sizes, int n_in,
                              void* d_out, int out_size, void* d_ws, size_t ws_size,
                              hipStream_t stream) {
    const float* u     = (const float*)d_in[0];
    const float* delta = (const float*)d_in[1];
    const float* A     = (const float*)d_in[2];
    const float* Bm    = (const float*)d_in[3];
    const float* Cm    = (const float*)d_in[4];
    const float* Dv    = (const float*)d_in[5];
    const float* z     = (const float*)d_in[6];
    float* out = (float*)d_out;
    float* ws = (float*)d_ws;

    size_t need64 = (size_t)(NSTATE + 1) * 64 * NCH * sizeof(float);
    size_t need32 = (size_t)(NSTATE + 1) * 32 * NCH * sizeof(float);
    size_t need16 = (size_t)(NSTATE + 1) * 16 * NCH * sizeof(float);
    if (ws_size >= need64) {
        launch_chunked<64>(u, delta, A, Bm, Cm, Dv, z, ws, out, stream);
    } else if (ws_size >= need32) {
        launch_chunked<32>(u, delta, A, Bm, Cm, Dv, z, ws, out, stream);
    } else if (ws_size >= need16) {
        launch_chunked<16>(u, delta, A, Bm, Cm, Dv, z, ws, out, stream);
    } else {
        k_simple<<<NCH / 256, 256, 0, stream>>>(u, delta, A, Bm, Cm, Dv, z, out);
    }
}